// Round 6
// baseline (148.852 us; speedup 1.0000x reference)
//
#include <hip/hip_runtime.h>

// CRF loss, B=1024, T=512, K=32 — chunked associative scan, FULLY FUSED.
//
// One kernel, one WG (512 thr = 8 waves) per sequence. Wave wv owns chunk
// c=wv (CHL=64 steps): N <- D_t (E^T N), register-resident:
//   * contraction index k is PERMUTED (pi: slot q*8+j <-> orig row q*4+j /
//     16+q*4+j-4). A (= E^T, constant) is packed in pi-order; under pi the
//     next step's B-fragment IS the current lane's own C fragments ->
//     NO LDS and NO cross-lane ops in the serial loop.
//   * emit exps staged per 32-step sub-stage into per-wave LDS (4 KB), next
//     stage's raw emits prefetched into 4 float4 regs (global latency hides
//     under the 32-step block).
//   * r5 post-mortem: duration was invariant under occupancy doubling ->
//     per-step VALU instruction count is the binding resource (~60 measured
//     vs ~16 floor). This version removes the big non-floor consumers:
//       - hoisted zero accumulator zf as MFMA C-in (was 16 v_mov/step)
//       - renorm keyed on COMPILE-TIME stage index (i&7)==7, not a dynamic
//         `applied` counter (renorm is exact bookkeeping at any point;
//         `applied` for the 2^-5-per-step compensation = popcount(ballot))
//       - dedicated unrolled path for chunk-0's 0xFFFFFFFE ballot
//   * step = 4x mfma_16x16x32_bf16 + 2 ds_read_b128 + 8 pk_mul + 8 v_perm
// Then each wave dumps M^T + (Slog, pathscore) into its own DEAD exp buffer,
// __syncthreads, wave 0 runs the serial combine (8 matvecs, rolling reg
// prefetch) and writes out[seq]. Single dispatch (the ~76 µs total-vs-kernel
// gap is harness-fixed reset overhead, insensitive to kernel structure).
//
// Per-wave LDS map (1024 dwords = expAll[wv]):
//   during scan : dwords 0..1023 = exp(emit) for current 32-step stage
//   after scan  : dwords 0..639 = transpose scratch (col-major, stride 20)
//                 then dwords 0..511 = M^T row-major bf16x2 (row*16 + d)
//                 dwords 1016/1017 = Slog / path-score

#define K32 32
#define Tt  512
#define NCH 8
#define CHL 64
#define NST 2
#define STL 32

typedef float  float4v __attribute__((ext_vector_type(4)));
typedef short  short8v __attribute__((ext_vector_type(8)));

__device__ inline float bf2f_lo(unsigned d) { return __uint_as_float(d << 16); }
__device__ inline float bf2f_hi(unsigned d) { return __uint_as_float(d & 0xFFFF0000u); }

// pack two f32 -> bf16x2 dword by truncation: low16 = hi16(lo), high16 = hi16(hi)
__device__ inline unsigned pack_trunc(float hi, float lo) {
    return __builtin_amdgcn_perm(__float_as_uint(hi), __float_as_uint(lo), 0x07060302u);
}
// round-to-nearest-even bf16 (one-time constants only)
__device__ inline unsigned short f2bf_rne(float x) {
    unsigned u = __float_as_uint(x);
    return (unsigned short)((u + 0x7FFFu + ((u >> 16) & 1u)) >> 16);
}

union F8 { unsigned u[4]; short8v v; };

__global__ __launch_bounds__(512, 8) void crf_fused(
    const int*   __restrict__ labels,
    const float* __restrict__ y_pred,
    const float* __restrict__ trans,
    const float* __restrict__ mask,
    float*       __restrict__ out)
{
    __shared__ float expAll[8][1024];         // 32 KB total -> 4 WG/CU

    const int lane = threadIdx.x & 63;
    const int wv   = __builtin_amdgcn_readfirstlane(threadIdx.x >> 6);  // wave-uniform
    const int n    = lane & 15;
    const int q    = lane >> 4;
    const int seq  = blockIdx.x;              // scalar
    const int c    = wv;                      // chunk id == wave id

    float* eb = &expAll[wv][0];

    const float* yp  = y_pred + (size_t)seq * Tt * K32;
    const int*   lb  = labels + (size_t)seq * Tt;
    const float* mkp = mask   + (size_t)seq * Tt;
    const int tbase = c * CHL;                // scalar

    // ---- prefetch stage-0 emits first (latency overlaps the score gather) ----
    float4 pre[4];
    {
        const float4* gs = (const float4*)(yp + (size_t)tbase * K32);
#pragma unroll
        for (int jj = 0; jj < 4; ++jj) pre[jj] = gs[jj * 64 + lane];
    }

    // ---- chunk path score + mask ballot (64 lanes <-> 64 timesteps) ----
    float sc;
    float mlane;
    {
        const int t = tbase + lane;
        const int lab0 = lb[t];
        mlane = mkp[t];
        sc = yp[t * K32 + lab0] * mlane;
        if (t < Tt - 1) {
            sc += trans[lab0 * K32 + lb[t + 1]] * (mlane * mkp[t + 1]);
        }
#pragma unroll
        for (int s = 1; s < 64; s <<= 1) sc += __shfl_xor(sc, s, 64);
    }
    unsigned long long mbits = __ballot(mlane != 0.0f);
    if (c == 0) mbits &= ~1ull;               // skip t=0 (alpha0 seeds combine)
    const int applied = __popcll(mbits);      // steps actually multiplied in

    // ---- constant A in pi-k-order: slot q*8+j <-> orig k = q*4+j | 16+q*4+(j-2) ----
    F8 AE0, AE1;
#pragma unroll
    for (int h = 0; h < 4; ++h) {
        const int k0 = (h < 2) ? (q * 4 + 2 * h) : (16 + q * 4 + 2 * (h - 2));
        const int k1 = k0 + 1;
        AE0.u[h] = ((unsigned)f2bf_rne(__expf(trans[k0 * K32 + n]) * 0.03125f)) |
                   (((unsigned)f2bf_rne(__expf(trans[k1 * K32 + n]) * 0.03125f)) << 16);
        AE1.u[h] = ((unsigned)f2bf_rne(__expf(trans[k0 * K32 + 16 + n]) * 0.03125f)) |
                   (((unsigned)f2bf_rne(__expf(trans[k1 * K32 + 16 + n]) * 0.03125f)) << 16);
    }

    // ---- B = identity fragments (pi-order) ----
    F8 B0, B1;
#pragma unroll
    for (int h = 0; h < 4; ++h) {
        const int r0 = (h < 2) ? (q * 4 + 2 * h) : (16 + q * 4 + 2 * (h - 2));
        const int r1 = r0 + 1;
        unsigned w0 = 0, w1 = 0;
        if (r0 == n)      w0 |= 0x3F80u;
        if (r1 == n)      w0 |= 0x3F800000u;
        if (r0 == 16 + n) w1 |= 0x3F80u;
        if (r1 == 16 + n) w1 |= 0x3F800000u;
        B0.u[h] = w0;
        B1.u[h] = w1;
    }

    const float4v zf = {0.f, 0.f, 0.f, 0.f};  // hoisted MFMA C-in (never written)
    float Slog = 0.0f;

    const int svoff0 = q * 4;                 // lane-const LDS float offsets
    const int svoff1 = 16 + q * 4;

    auto step = [&](int i, bool ren) {        // one scan step, stage-local index i
        const float4v sv0 = *(const float4v*)&eb[i * 32 + svoff0];
        const float4v sv1 = *(const float4v*)&eb[i * 32 + svoff1];

        float4v c00 = __builtin_amdgcn_mfma_f32_16x16x32_bf16(AE0.v, B0.v, zf, 0, 0, 0);
        float4v c01 = __builtin_amdgcn_mfma_f32_16x16x32_bf16(AE0.v, B1.v, zf, 0, 0, 0);
        float4v c10 = __builtin_amdgcn_mfma_f32_16x16x32_bf16(AE1.v, B0.v, zf, 0, 0, 0);
        float4v c11 = __builtin_amdgcn_mfma_f32_16x16x32_bf16(AE1.v, B1.v, zf, 0, 0, 0);

        // D_t row-scale
        c00 *= sv0; c01 *= sv0; c10 *= sv1; c11 *= sv1;

        if (ren) {                            // exact bookkeeping; any point valid
            const float cn = __uint_as_float(
                __builtin_amdgcn_readfirstlane(__float_as_uint(c00[0])));
            const float rs = 1.0f / cn;
            c00 *= rs; c01 *= rs; c10 *= rs; c11 *= rs;
            Slog += __logf(cn);
        }

        // pack C -> next B (pi-order makes this the lane's own data)
        B0.u[0] = pack_trunc(c00[1], c00[0]);
        B0.u[1] = pack_trunc(c00[3], c00[2]);
        B0.u[2] = pack_trunc(c10[1], c10[0]);
        B0.u[3] = pack_trunc(c10[3], c10[2]);
        B1.u[0] = pack_trunc(c01[1], c01[0]);
        B1.u[1] = pack_trunc(c01[3], c01[2]);
        B1.u[2] = pack_trunc(c11[1], c11[0]);
        B1.u[3] = pack_trunc(c11[3], c11[2]);
    };

    for (int st = 0; st < NST; ++st) {
        // ---- exp + stage one 32-step block from prefetched regs ----
#pragma unroll
        for (int jj = 0; jj < 4; ++jj) {
            const float4 pv = pre[jj];
            float4v e;
            e[0] = __expf(pv.x); e[1] = __expf(pv.y);
            e[2] = __expf(pv.z); e[3] = __expf(pv.w);
            *(float4v*)&eb[(jj * 64 + lane) * 4] = e;
        }
        // ---- prefetch next stage (hides HBM latency under the step loop) ----
        if (st + 1 < NST) {
            const float4* gs = (const float4*)(yp + (size_t)(tbase + (st + 1) * STL) * K32);
#pragma unroll
            for (int jj = 0; jj < 4; ++jj) pre[jj] = gs[jj * 64 + lane];
        }

        const unsigned b32 = (unsigned)(mbits >> (st * 32));
        if (b32 == 0xFFFFFFFFu) {
            // branch-free fast path; renorm position compile-time
#pragma unroll
            for (int g = 0; g < 4; ++g) {
                step(g * 8 + 0, false); step(g * 8 + 1, false);
                step(g * 8 + 2, false); step(g * 8 + 3, false);
                step(g * 8 + 4, false); step(g * 8 + 5, false);
                step(g * 8 + 6, false); step(g * 8 + 7, true);
            }
        } else if (b32 == 0xFFFFFFFEu) {
            // chunk-0 stage-0 common case: skip step 0, rest branch-free
#pragma unroll
            for (int g = 0; g < 4; ++g) {
                if (g != 0) step(g * 8 + 0, false);
                step(g * 8 + 1, false); step(g * 8 + 2, false);
                step(g * 8 + 3, false); step(g * 8 + 4, false);
                step(g * 8 + 5, false); step(g * 8 + 6, false);
                step(g * 8 + 7, true);
            }
        } else {
            for (int i = 0; i < STL; ++i) {
                if ((b32 >> i) & 1u) step(i, (i & 7) == 7);
            }
        }
    }

    // ---- transpose in-place in the dead exp buffer (1024 dwords) ----
    {
        unsigned* Nd = (unsigned*)eb;             // col-major scratch, stride 20
        *(uint2*)&Nd[n * 20 + q * 2]            = make_uint2(B0.u[0], B0.u[1]);
        *(uint2*)&Nd[n * 20 + 8 + q * 2]        = make_uint2(B0.u[2], B0.u[3]);
        *(uint2*)&Nd[(16 + n) * 20 + q * 2]     = make_uint2(B1.u[0], B1.u[1]);
        *(uint2*)&Nd[(16 + n) * 20 + 8 + q * 2] = make_uint2(B1.u[2], B1.u[3]);
    }
    {
        // read all pieces to regs, then overwrite region with M^T row-major.
        // (wave-private; LDS ops in order; all reads precede all writes.)
        const unsigned short* Ncm = (const unsigned short*)eb;
        unsigned r[8];
#pragma unroll
        for (int ii = 0; ii < 8; ++ii) {
            const int idx = ii * 64 + lane;
            const int k = idx >> 4, d = idx & 15;
            r[ii] = (unsigned)Ncm[(2 * d) * 40 + k] |
                    ((unsigned)Ncm[(2 * d + 1) * 40 + k] << 16);
        }
        unsigned* md = (unsigned*)eb;             // M^T: dword = row*16 + d
#pragma unroll
        for (int ii = 0; ii < 8; ++ii) md[ii * 64 + lane] = r[ii];
    }
    if (lane == 0) {
        eb[1016] = Slog + (float)applied * 3.46573590f;   // + applied*5*ln2
        eb[1017] = sc;
    }

    __syncthreads();

    // ---------------- combine (wave 0 only): 8 serial matvecs + logsumexp ----------------
    if (wv == 0) {
        const int h = lane >> 5;
        const int j = lane & 31;

        // rolling 1-chunk register prefetch of M^T row j halves (keeps VGPR low)
        uint4 cA, cB;
        {
            const unsigned* mt = (const unsigned*)&expAll[0][0];
            cA = *(const uint4*)&mt[j * 16 + 8 * h];
            cB = *(const uint4*)&mt[j * 16 + 8 * h + 4];
        }

        const float a0 = yp[j];                // mirrored in both halves
        const float m0 = __shfl(a0, 0, 64);
        float p = __expf(a0 - m0);             // p[j], mirrored
        float S = m0;

        float scs = 0.0f;
#pragma unroll
        for (int cc = 0; cc < NCH; ++cc) {
            S   += expAll[cc][1016];
            scs += expAll[cc][1017];
        }

        const int cb = h << 4;                 // column base for this half
#pragma unroll
        for (int cc = 0; cc < NCH; ++cc) {
            uint4 nA = {0, 0, 0, 0}, nB = {0, 0, 0, 0};
            if (cc + 1 < NCH) {
                const unsigned* mt = (const unsigned*)&expAll[cc + 1][0];
                nA = *(const uint4*)&mt[j * 16 + 8 * h];
                nB = *(const uint4*)&mt[j * 16 + 8 * h + 4];
            }
            const float cn = __shfl(p, 0, 64); // old p[0] (deferred renorm)
            const unsigned u0 = cA.x, u1 = cA.y, u2 = cA.z, u3 = cA.w;
            const unsigned u4 = cB.x, u5 = cB.y, u6 = cB.z, u7 = cB.w;
            float acc = 0.0f;
            acc = fmaf(__shfl(p, cb +  0, 64), bf2f_lo(u0), acc);
            acc = fmaf(__shfl(p, cb +  1, 64), bf2f_hi(u0), acc);
            acc = fmaf(__shfl(p, cb +  2, 64), bf2f_lo(u1), acc);
            acc = fmaf(__shfl(p, cb +  3, 64), bf2f_hi(u1), acc);
            acc = fmaf(__shfl(p, cb +  4, 64), bf2f_lo(u2), acc);
            acc = fmaf(__shfl(p, cb +  5, 64), bf2f_hi(u2), acc);
            acc = fmaf(__shfl(p, cb +  6, 64), bf2f_lo(u3), acc);
            acc = fmaf(__shfl(p, cb +  7, 64), bf2f_hi(u3), acc);
            acc = fmaf(__shfl(p, cb +  8, 64), bf2f_lo(u4), acc);
            acc = fmaf(__shfl(p, cb +  9, 64), bf2f_hi(u4), acc);
            acc = fmaf(__shfl(p, cb + 10, 64), bf2f_lo(u5), acc);
            acc = fmaf(__shfl(p, cb + 11, 64), bf2f_hi(u5), acc);
            acc = fmaf(__shfl(p, cb + 12, 64), bf2f_lo(u6), acc);
            acc = fmaf(__shfl(p, cb + 13, 64), bf2f_hi(u6), acc);
            acc = fmaf(__shfl(p, cb + 14, 64), bf2f_lo(u7), acc);
            acc = fmaf(__shfl(p, cb + 15, 64), bf2f_hi(u7), acc);
            acc += __shfl_xor(acc, 32, 64);    // combine halves -> full dot, mirrored
            p = acc * (1.0f / cn);
            S += __logf(cn);
            cA = nA; cB = nB;
        }

        float sp = p;
        sp += __shfl_xor(sp,  1, 64);
        sp += __shfl_xor(sp,  2, 64);
        sp += __shfl_xor(sp,  4, 64);
        sp += __shfl_xor(sp,  8, 64);
        sp += __shfl_xor(sp, 16, 64);

        if (lane == 0) {
            out[seq] = S + __logf(sp) - scs;
        }
    }
}

extern "C" void kernel_launch(void* const* d_in, const int* in_sizes, int n_in,
                              void* d_out, int out_size, void* d_ws, size_t ws_size,
                              hipStream_t stream) {
    const int*   labels = (const int*)  d_in[0];
    const float* y_pred = (const float*)d_in[1];
    const float* trans  = (const float*)d_in[2];
    const float* mask   = (const float*)d_in[3];
    float* out = (float*)d_out;

    crf_fused<<<1024, 512, 0, stream>>>(labels, y_pred, trans, mask, out);
}

// Round 7
// 136.987 us; speedup vs baseline: 1.0866x; 1.0866x over previous
//
#include <hip/hip_runtime.h>

// CRF loss, B=1024, T=512, K=32 — chunked associative scan, FULLY FUSED.
//
// One kernel, one WG (512 thr = 8 waves) per sequence. Wave wv owns chunk
// c=wv (CHL=64 steps): N <- D_t (E^T N), register-resident:
//   * contraction index k is PERMUTED (pi: slot q*8+j <-> orig row q*4+j /
//     16+q*4+j-4). A (= E^T, constant) is packed in pi-order; under pi the
//     next step's B-fragment IS the current lane's own C fragments ->
//     NO LDS and NO cross-lane ops in the serial loop.
//   * emit exps staged per 32-step sub-stage into per-wave LDS (4 KB).
//     Stage-0 emits prefetched before the score gather (regs die at first
//     staging — before the high-pressure unrolled region). Stage 1 loads
//     directly (latency hidden by 8-wave TLP; r4/r5 showed prefetch-vs-not
//     is speed-neutral, but holding it across the step loop costs 16 VGPRs).
//   * per-step VALU floor (r5/r6 analysis): hoisted zero C-in (zf), renorm
//     keyed on compile-time stage index (i&7)==7, applied = popcount(ballot),
//     dedicated unrolled path for chunk-0's 0xFFFFFFFE ballot.
//   * step = 4x mfma_16x16x32_bf16 + 2 ds_read_b128 + 8 pk_mul + 8 v_perm
//   * LAUNCH BOUNDS: hipcc treats the 2nd arg as WORKGROUPS/CU (CUDA
//     minBlocks semantics): r5/r6's (512,8) demanded 8 WG/CU -> 32-VGPR cap
//     -> 6-55 MB of scratch-spill writes (WRITE_SIZE counter). (512,4) =
//     4 WG/CU (the LDS limit anyway) -> 64-VGPR cap, zero spill.
// Then each wave dumps M^T + (Slog, pathscore) into its own DEAD exp buffer,
// __syncthreads, wave 0 runs the serial combine (8 matvecs, rolling reg
// prefetch) and writes out[seq]. Single dispatch (the ~76 µs total-vs-kernel
// gap is harness-fixed reset overhead, insensitive to kernel structure).
//
// Per-wave LDS map (1024 dwords = expAll[wv]):
//   during scan : dwords 0..1023 = exp(emit) for current 32-step stage
//   after scan  : dwords 0..639 = transpose scratch (col-major, stride 20)
//                 then dwords 0..511 = M^T row-major bf16x2 (row*16 + d)
//                 dwords 1016/1017 = Slog / path-score

#define K32 32
#define Tt  512
#define NCH 8
#define CHL 64
#define NST 2
#define STL 32

typedef float  float4v __attribute__((ext_vector_type(4)));
typedef short  short8v __attribute__((ext_vector_type(8)));

__device__ inline float bf2f_lo(unsigned d) { return __uint_as_float(d << 16); }
__device__ inline float bf2f_hi(unsigned d) { return __uint_as_float(d & 0xFFFF0000u); }

// pack two f32 -> bf16x2 dword by truncation: low16 = hi16(lo), high16 = hi16(hi)
__device__ inline unsigned pack_trunc(float hi, float lo) {
    return __builtin_amdgcn_perm(__float_as_uint(hi), __float_as_uint(lo), 0x07060302u);
}
// round-to-nearest-even bf16 (one-time constants only)
__device__ inline unsigned short f2bf_rne(float x) {
    unsigned u = __float_as_uint(x);
    return (unsigned short)((u + 0x7FFFu + ((u >> 16) & 1u)) >> 16);
}

union F8 { unsigned u[4]; short8v v; };

__global__ __launch_bounds__(512, 4) void crf_fused(
    const int*   __restrict__ labels,
    const float* __restrict__ y_pred,
    const float* __restrict__ trans,
    const float* __restrict__ mask,
    float*       __restrict__ out)
{
    __shared__ float expAll[8][1024];         // 32 KB total -> 4 WG/CU

    const int lane = threadIdx.x & 63;
    const int wv   = __builtin_amdgcn_readfirstlane(threadIdx.x >> 6);  // wave-uniform
    const int n    = lane & 15;
    const int q    = lane >> 4;
    const int seq  = blockIdx.x;              // scalar
    const int c    = wv;                      // chunk id == wave id

    float* eb = &expAll[wv][0];

    const float* yp  = y_pred + (size_t)seq * Tt * K32;
    const int*   lb  = labels + (size_t)seq * Tt;
    const float* mkp = mask   + (size_t)seq * Tt;
    const int tbase = c * CHL;                // scalar

    // ---- prefetch stage-0 emits (latency overlaps the score gather; these
    //      registers die at the first staging, before peak pressure) ----
    float4 pre[4];
    {
        const float4* gs = (const float4*)(yp + (size_t)tbase * K32);
#pragma unroll
        for (int jj = 0; jj < 4; ++jj) pre[jj] = gs[jj * 64 + lane];
    }

    // ---- chunk path score + mask ballot (64 lanes <-> 64 timesteps) ----
    float sc;
    float mlane;
    {
        const int t = tbase + lane;
        const int lab0 = lb[t];
        mlane = mkp[t];
        sc = yp[t * K32 + lab0] * mlane;
        if (t < Tt - 1) {
            sc += trans[lab0 * K32 + lb[t + 1]] * (mlane * mkp[t + 1]);
        }
#pragma unroll
        for (int s = 1; s < 64; s <<= 1) sc += __shfl_xor(sc, s, 64);
    }
    unsigned long long mbits = __ballot(mlane != 0.0f);
    if (c == 0) mbits &= ~1ull;               // skip t=0 (alpha0 seeds combine)
    const int applied = __popcll(mbits);      // steps actually multiplied in

    // ---- constant A in pi-k-order: slot q*8+j <-> orig k = q*4+j | 16+q*4+(j-2) ----
    F8 AE0, AE1;
#pragma unroll
    for (int h = 0; h < 4; ++h) {
        const int k0 = (h < 2) ? (q * 4 + 2 * h) : (16 + q * 4 + 2 * (h - 2));
        const int k1 = k0 + 1;
        AE0.u[h] = ((unsigned)f2bf_rne(__expf(trans[k0 * K32 + n]) * 0.03125f)) |
                   (((unsigned)f2bf_rne(__expf(trans[k1 * K32 + n]) * 0.03125f)) << 16);
        AE1.u[h] = ((unsigned)f2bf_rne(__expf(trans[k0 * K32 + 16 + n]) * 0.03125f)) |
                   (((unsigned)f2bf_rne(__expf(trans[k1 * K32 + 16 + n]) * 0.03125f)) << 16);
    }

    // ---- B = identity fragments (pi-order) ----
    F8 B0, B1;
#pragma unroll
    for (int h = 0; h < 4; ++h) {
        const int r0 = (h < 2) ? (q * 4 + 2 * h) : (16 + q * 4 + 2 * (h - 2));
        const int r1 = r0 + 1;
        unsigned w0 = 0, w1 = 0;
        if (r0 == n)      w0 |= 0x3F80u;
        if (r1 == n)      w0 |= 0x3F800000u;
        if (r0 == 16 + n) w1 |= 0x3F80u;
        if (r1 == 16 + n) w1 |= 0x3F800000u;
        B0.u[h] = w0;
        B1.u[h] = w1;
    }

    const float4v zf = {0.f, 0.f, 0.f, 0.f};  // hoisted MFMA C-in (never written)
    float Slog = 0.0f;

    const int svoff0 = q * 4;                 // lane-const LDS float offsets
    const int svoff1 = 16 + q * 4;

    auto step = [&](int i, bool ren) {        // one scan step, stage-local index i
        const float4v sv0 = *(const float4v*)&eb[i * 32 + svoff0];
        const float4v sv1 = *(const float4v*)&eb[i * 32 + svoff1];

        float4v c00 = __builtin_amdgcn_mfma_f32_16x16x32_bf16(AE0.v, B0.v, zf, 0, 0, 0);
        float4v c01 = __builtin_amdgcn_mfma_f32_16x16x32_bf16(AE0.v, B1.v, zf, 0, 0, 0);
        float4v c10 = __builtin_amdgcn_mfma_f32_16x16x32_bf16(AE1.v, B0.v, zf, 0, 0, 0);
        float4v c11 = __builtin_amdgcn_mfma_f32_16x16x32_bf16(AE1.v, B1.v, zf, 0, 0, 0);

        // D_t row-scale
        c00 *= sv0; c01 *= sv0; c10 *= sv1; c11 *= sv1;

        if (ren) {                            // exact bookkeeping; any point valid
            const float cn = __uint_as_float(
                __builtin_amdgcn_readfirstlane(__float_as_uint(c00[0])));
            const float rs = 1.0f / cn;
            c00 *= rs; c01 *= rs; c10 *= rs; c11 *= rs;
            Slog += __logf(cn);
        }

        // pack C -> next B (pi-order makes this the lane's own data)
        B0.u[0] = pack_trunc(c00[1], c00[0]);
        B0.u[1] = pack_trunc(c00[3], c00[2]);
        B0.u[2] = pack_trunc(c10[1], c10[0]);
        B0.u[3] = pack_trunc(c10[3], c10[2]);
        B1.u[0] = pack_trunc(c01[1], c01[0]);
        B1.u[1] = pack_trunc(c01[3], c01[2]);
        B1.u[2] = pack_trunc(c11[1], c11[0]);
        B1.u[3] = pack_trunc(c11[3], c11[2]);
    };

#pragma unroll
    for (int st = 0; st < NST; ++st) {
        // ---- exp + stage one 32-step block (per-wave private LDS) ----
        if (st == 0) {
#pragma unroll
            for (int jj = 0; jj < 4; ++jj) {
                const float4 pv = pre[jj];
                float4v e;
                e[0] = __expf(pv.x); e[1] = __expf(pv.y);
                e[2] = __expf(pv.z); e[3] = __expf(pv.w);
                *(float4v*)&eb[(jj * 64 + lane) * 4] = e;
            }
        } else {
            const float4* gs = (const float4*)(yp + (size_t)(tbase + st * STL) * K32);
#pragma unroll
            for (int jj = 0; jj < 4; ++jj) {
                const float4 pv = gs[jj * 64 + lane];
                float4v e;
                e[0] = __expf(pv.x); e[1] = __expf(pv.y);
                e[2] = __expf(pv.z); e[3] = __expf(pv.w);
                *(float4v*)&eb[(jj * 64 + lane) * 4] = e;
            }
        }

        const unsigned b32 = (unsigned)(mbits >> (st * 32));
        if (b32 == 0xFFFFFFFFu) {
            // branch-free fast path; renorm position compile-time
#pragma unroll
            for (int g = 0; g < 4; ++g) {
                step(g * 8 + 0, false); step(g * 8 + 1, false);
                step(g * 8 + 2, false); step(g * 8 + 3, false);
                step(g * 8 + 4, false); step(g * 8 + 5, false);
                step(g * 8 + 6, false); step(g * 8 + 7, true);
            }
        } else if (b32 == 0xFFFFFFFEu) {
            // chunk-0 stage-0 common case: skip step 0, rest branch-free
#pragma unroll
            for (int g = 0; g < 4; ++g) {
                if (g != 0) step(g * 8 + 0, false);
                step(g * 8 + 1, false); step(g * 8 + 2, false);
                step(g * 8 + 3, false); step(g * 8 + 4, false);
                step(g * 8 + 5, false); step(g * 8 + 6, false);
                step(g * 8 + 7, true);
            }
        } else {
            for (int i = 0; i < STL; ++i) {
                if ((b32 >> i) & 1u) step(i, (i & 7) == 7);
            }
        }
    }

    // ---- transpose in-place in the dead exp buffer (1024 dwords) ----
    {
        unsigned* Nd = (unsigned*)eb;             // col-major scratch, stride 20
        *(uint2*)&Nd[n * 20 + q * 2]            = make_uint2(B0.u[0], B0.u[1]);
        *(uint2*)&Nd[n * 20 + 8 + q * 2]        = make_uint2(B0.u[2], B0.u[3]);
        *(uint2*)&Nd[(16 + n) * 20 + q * 2]     = make_uint2(B1.u[0], B1.u[1]);
        *(uint2*)&Nd[(16 + n) * 20 + 8 + q * 2] = make_uint2(B1.u[2], B1.u[3]);
    }
    {
        // read all pieces to regs, then overwrite region with M^T row-major.
        // (wave-private; LDS ops in order; all reads precede all writes.)
        const unsigned short* Ncm = (const unsigned short*)eb;
        unsigned r[8];
#pragma unroll
        for (int ii = 0; ii < 8; ++ii) {
            const int idx = ii * 64 + lane;
            const int k = idx >> 4, d = idx & 15;
            r[ii] = (unsigned)Ncm[(2 * d) * 40 + k] |
                    ((unsigned)Ncm[(2 * d + 1) * 40 + k] << 16);
        }
        unsigned* md = (unsigned*)eb;             // M^T: dword = row*16 + d
#pragma unroll
        for (int ii = 0; ii < 8; ++ii) md[ii * 64 + lane] = r[ii];
    }
    if (lane == 0) {
        eb[1016] = Slog + (float)applied * 3.46573590f;   // + applied*5*ln2
        eb[1017] = sc;
    }

    __syncthreads();

    // ---------------- combine (wave 0 only): 8 serial matvecs + logsumexp ----------------
    if (wv == 0) {
        const int h = lane >> 5;
        const int j = lane & 31;

        // rolling 1-chunk register prefetch of M^T row j halves (keeps VGPR low)
        uint4 cA, cB;
        {
            const unsigned* mt = (const unsigned*)&expAll[0][0];
            cA = *(const uint4*)&mt[j * 16 + 8 * h];
            cB = *(const uint4*)&mt[j * 16 + 8 * h + 4];
        }

        const float a0 = yp[j];                // mirrored in both halves
        const float m0 = __shfl(a0, 0, 64);
        float p = __expf(a0 - m0);             // p[j], mirrored
        float S = m0;

        float scs = 0.0f;
#pragma unroll
        for (int cc = 0; cc < NCH; ++cc) {
            S   += expAll[cc][1016];
            scs += expAll[cc][1017];
        }

        const int cb = h << 4;                 // column base for this half
#pragma unroll
        for (int cc = 0; cc < NCH; ++cc) {
            uint4 nA = {0, 0, 0, 0}, nB = {0, 0, 0, 0};
            if (cc + 1 < NCH) {
                const unsigned* mt = (const unsigned*)&expAll[cc + 1][0];
                nA = *(const uint4*)&mt[j * 16 + 8 * h];
                nB = *(const uint4*)&mt[j * 16 + 8 * h + 4];
            }
            const float cn = __shfl(p, 0, 64); // old p[0] (deferred renorm)
            const unsigned u0 = cA.x, u1 = cA.y, u2 = cA.z, u3 = cA.w;
            const unsigned u4 = cB.x, u5 = cB.y, u6 = cB.z, u7 = cB.w;
            float acc = 0.0f;
            acc = fmaf(__shfl(p, cb +  0, 64), bf2f_lo(u0), acc);
            acc = fmaf(__shfl(p, cb +  1, 64), bf2f_hi(u0), acc);
            acc = fmaf(__shfl(p, cb +  2, 64), bf2f_lo(u1), acc);
            acc = fmaf(__shfl(p, cb +  3, 64), bf2f_hi(u1), acc);
            acc = fmaf(__shfl(p, cb +  4, 64), bf2f_lo(u2), acc);
            acc = fmaf(__shfl(p, cb +  5, 64), bf2f_hi(u2), acc);
            acc = fmaf(__shfl(p, cb +  6, 64), bf2f_lo(u3), acc);
            acc = fmaf(__shfl(p, cb +  7, 64), bf2f_hi(u3), acc);
            acc = fmaf(__shfl(p, cb +  8, 64), bf2f_lo(u4), acc);
            acc = fmaf(__shfl(p, cb +  9, 64), bf2f_hi(u4), acc);
            acc = fmaf(__shfl(p, cb + 10, 64), bf2f_lo(u5), acc);
            acc = fmaf(__shfl(p, cb + 11, 64), bf2f_hi(u5), acc);
            acc = fmaf(__shfl(p, cb + 12, 64), bf2f_lo(u6), acc);
            acc = fmaf(__shfl(p, cb + 13, 64), bf2f_hi(u6), acc);
            acc = fmaf(__shfl(p, cb + 14, 64), bf2f_lo(u7), acc);
            acc = fmaf(__shfl(p, cb + 15, 64), bf2f_hi(u7), acc);
            acc += __shfl_xor(acc, 32, 64);    // combine halves -> full dot, mirrored
            p = acc * (1.0f / cn);
            S += __logf(cn);
            cA = nA; cB = nB;
        }

        float sp = p;
        sp += __shfl_xor(sp,  1, 64);
        sp += __shfl_xor(sp,  2, 64);
        sp += __shfl_xor(sp,  4, 64);
        sp += __shfl_xor(sp,  8, 64);
        sp += __shfl_xor(sp, 16, 64);

        if (lane == 0) {
            out[seq] = S + __logf(sp) - scs;
        }
    }
}

extern "C" void kernel_launch(void* const* d_in, const int* in_sizes, int n_in,
                              void* d_out, int out_size, void* d_ws, size_t ws_size,
                              hipStream_t stream) {
    const int*   labels = (const int*)  d_in[0];
    const float* y_pred = (const float*)d_in[1];
    const float* trans  = (const float*)d_in[2];
    const float* mask   = (const float*)d_in[3];
    float* out = (float*)d_out;

    crf_fused<<<1024, 512, 0, stream>>>(labels, y_pred, trans, mask, out);
}

// Round 8
// 135.433 us; speedup vs baseline: 1.0991x; 1.0115x over previous
//
#include <hip/hip_runtime.h>

// CRF loss, B=1024, T=512, K=32 — chunked associative scan, FULLY FUSED,
// TWO INDEPENDENT CHUNKS PER WAVE (ILP experiment).
//
// One WG (256 thr = 4 waves) per sequence. Wave wv owns chunks 2wv and 2wv+1
// (NCH=8 global chunks, CHL=64), processing their scan steps INTERLEAVED:
// each step-pair issues 8 INDEPENDENT mfma_16x16x32_bf16 (4 per chunk).
// Rationale (r4/r5/r7 post-mortems): duration was invariant at ~62-65 µs
// across 4-vs-8 waves/SIMD and across per-step VALU cuts — per-SIMD time is
// pinned at ~290 cycles per step-instance vs ~100 cycles of issue content.
// Cross-wave overlap is not filling the pipe; this doubles PER-WAVE
// independent chains instead (2 chunks × 2 column-halves = 4 chains/wave).
//
//   * contraction index k is PERMUTED (pi) so next step's B-fragment IS the
//     lane's own C fragments -> no LDS/cross-lane in the serial loop.
//   * emit exps staged per 32-step stage into per-wave LDS: chunk A at
//     eb[0..1023], chunk B at eb[1024..2047] (8 KB/wave, 32 KB/WG, 4 WG/CU).
//   * renorm every 8 steps per chain: EXACT power-of-2 exponent strip
//     (readfirstlane -> SALU bitops; no rcp/logf on the chain; Slog becomes
//     integer eSum x ln2 + applied x 5ln2, applied = popcount(ballot)).
//   * launch_bounds(256,4): VGPR cap 128 — holds 2x chunk state w/o spills
//     (r6 lesson: (512,8) meant 8 WG/CU -> 32-VGPR cap -> 55 MB spill traffic;
//     WRITE_SIZE is the spill canary, must stay ~32 KB).
// Then per-wave: 2 transposes into dead LDS, wave 0 combines 8 matvecs and
// writes out[seq]. Single dispatch (~75 µs of harness reset overhead is fixed).
//
// Per-wave LDS map (2048 dwords = expAll[wv]):
//   scan      : [0..1023] chunk-A exp stage, [1024..2047] chunk-B exp stage
//   transpose : scratch at [1024..1663] (sequentially for A then B)
//               M^T A -> [0..511], M^T B -> [512..1023]
//   sAux[8]   : per-wave combined-Slog (0..3) and path-score (4..7)

#define K32 32
#define Tt  512
#define NCH 8
#define CHL 64
#define NST 2
#define STL 32

typedef float  float4v __attribute__((ext_vector_type(4)));
typedef short  short8v __attribute__((ext_vector_type(8)));

__device__ inline float bf2f_lo(unsigned d) { return __uint_as_float(d << 16); }
__device__ inline float bf2f_hi(unsigned d) { return __uint_as_float(d & 0xFFFF0000u); }

// pack two f32 -> bf16x2 dword by truncation: low16 = hi16(lo), high16 = hi16(hi)
__device__ inline unsigned pack_trunc(float hi, float lo) {
    return __builtin_amdgcn_perm(__float_as_uint(hi), __float_as_uint(lo), 0x07060302u);
}
// round-to-nearest-even bf16 (one-time constants only)
__device__ inline unsigned short f2bf_rne(float x) {
    unsigned u = __float_as_uint(x);
    return (unsigned short)((u + 0x7FFFu + ((u >> 16) & 1u)) >> 16);
}

union F8 { unsigned u[4]; short8v v; };

__global__ __launch_bounds__(256, 4) void crf_fused(
    const int*   __restrict__ labels,
    const float* __restrict__ y_pred,
    const float* __restrict__ trans,
    const float* __restrict__ mask,
    float*       __restrict__ out)
{
    __shared__ float expAll[4][2048];         // 32 KB -> 4 WG/CU
    __shared__ float sAux[8];

    const int lane = threadIdx.x & 63;
    const int wv   = __builtin_amdgcn_readfirstlane(threadIdx.x >> 6);  // wave-uniform
    const int n    = lane & 15;
    const int q    = lane >> 4;
    const int seq  = blockIdx.x;              // scalar

    float* ebA = &expAll[wv][0];
    float* ebB = ebA + 1024;

    const float* yp  = y_pred + (size_t)seq * Tt * K32;
    const int*   lb  = labels + (size_t)seq * Tt;
    const float* mkp = mask   + (size_t)seq * Tt;
    const int tbA = wv * 128;                 // chunk 2wv
    const int tbB = tbA + 64;                 // chunk 2wv+1

    // ---- prefetch stage-0 emits for BOTH chunks (die at first staging) ----
    float4 preA[4], preB[4];
    {
        const float4* gA = (const float4*)(yp + (size_t)tbA * K32);
        const float4* gB = (const float4*)(yp + (size_t)tbB * K32);
#pragma unroll
        for (int jj = 0; jj < 4; ++jj) { preA[jj] = gA[jj * 64 + lane]; preB[jj] = gB[jj * 64 + lane]; }
    }

    // ---- path scores + mask ballots for both chunks ----
    float sc;
    float mA, mB;
    {
        const int tA = tbA + lane;            // max 447 -> trans term always valid
        const int labA = lb[tA];
        mA = mkp[tA];
        float s = yp[tA * K32 + labA] * mA;
        s += trans[labA * K32 + lb[tA + 1]] * (mA * mkp[tA + 1]);

        const int tB = tbB + lane;            // max 511 -> guard last
        const int labB = lb[tB];
        mB = mkp[tB];
        float sB = yp[tB * K32 + labB] * mB;
        if (tB < Tt - 1) sB += trans[labB * K32 + lb[tB + 1]] * (mB * mkp[tB + 1]);

        sc = s + sB;
#pragma unroll
        for (int sft = 1; sft < 64; sft <<= 1) sc += __shfl_xor(sc, sft, 64);
    }
    unsigned long long mbA = __ballot(mA != 0.0f);
    unsigned long long mbB = __ballot(mB != 0.0f);
    if (wv == 0) mbA &= ~1ull;                // skip t=0 (alpha0 seeds combine)
    const int applied = __popcll(mbA) + __popcll(mbB);

    // ---- constant A in pi-k-order ----
    F8 AE0, AE1;
#pragma unroll
    for (int h = 0; h < 4; ++h) {
        const int k0 = (h < 2) ? (q * 4 + 2 * h) : (16 + q * 4 + 2 * (h - 2));
        const int k1 = k0 + 1;
        AE0.u[h] = ((unsigned)f2bf_rne(__expf(trans[k0 * K32 + n]) * 0.03125f)) |
                   (((unsigned)f2bf_rne(__expf(trans[k1 * K32 + n]) * 0.03125f)) << 16);
        AE1.u[h] = ((unsigned)f2bf_rne(__expf(trans[k0 * K32 + 16 + n]) * 0.03125f)) |
                   (((unsigned)f2bf_rne(__expf(trans[k1 * K32 + 16 + n]) * 0.03125f)) << 16);
    }

    // ---- identity B fragments (pi-order) for both chunks ----
    F8 BA0, BA1, BB0, BB1;
#pragma unroll
    for (int h = 0; h < 4; ++h) {
        const int r0 = (h < 2) ? (q * 4 + 2 * h) : (16 + q * 4 + 2 * (h - 2));
        const int r1 = r0 + 1;
        unsigned w0 = 0, w1 = 0;
        if (r0 == n)      w0 |= 0x3F80u;
        if (r1 == n)      w0 |= 0x3F800000u;
        if (r0 == 16 + n) w1 |= 0x3F80u;
        if (r1 == 16 + n) w1 |= 0x3F800000u;
        BA0.u[h] = w0; BA1.u[h] = w1;
        BB0.u[h] = w0; BB1.u[h] = w1;
    }

    const float4v zf = {0.f, 0.f, 0.f, 0.f};  // hoisted MFMA C-in
    int eSum = 0;                             // combined pow2-renorm exponent sum

    const int svoff0 = q * 4;
    const int svoff1 = 16 + q * 4;

    auto stepone = [&](const float* ebx, F8& B0, F8& B1, int i, bool ren) {
        const float4v sv0 = *(const float4v*)&ebx[i * 32 + svoff0];
        const float4v sv1 = *(const float4v*)&ebx[i * 32 + svoff1];

        float4v c00 = __builtin_amdgcn_mfma_f32_16x16x32_bf16(AE0.v, B0.v, zf, 0, 0, 0);
        float4v c01 = __builtin_amdgcn_mfma_f32_16x16x32_bf16(AE0.v, B1.v, zf, 0, 0, 0);
        float4v c10 = __builtin_amdgcn_mfma_f32_16x16x32_bf16(AE1.v, B0.v, zf, 0, 0, 0);
        float4v c11 = __builtin_amdgcn_mfma_f32_16x16x32_bf16(AE1.v, B1.v, zf, 0, 0, 0);

        c00 *= sv0; c01 *= sv0; c10 *= sv1; c11 *= sv1;

        if (ren) {                            // exact pow2 renorm: strip exponent of c00[0]
            const unsigned cb = __builtin_amdgcn_readfirstlane(__float_as_uint(c00[0]));
            const int e = (int)((cb >> 23) & 255u) - 127;
            const float rs = __uint_as_float((unsigned)(127 - e) << 23);  // 2^-e
            c00 *= rs; c01 *= rs; c10 *= rs; c11 *= rs;
            eSum += e;
        }

        B0.u[0] = pack_trunc(c00[1], c00[0]);
        B0.u[1] = pack_trunc(c00[3], c00[2]);
        B0.u[2] = pack_trunc(c10[1], c10[0]);
        B0.u[3] = pack_trunc(c10[3], c10[2]);
        B1.u[0] = pack_trunc(c01[1], c01[0]);
        B1.u[1] = pack_trunc(c01[3], c01[2]);
        B1.u[2] = pack_trunc(c11[1], c11[0]);
        B1.u[3] = pack_trunc(c11[3], c11[2]);
    };

    for (int st = 0; st < NST; ++st) {
        // ---- exp + stage one 32-step block per chunk (per-wave private) ----
        if (st == 0) {
#pragma unroll
            for (int jj = 0; jj < 4; ++jj) {
                float4v eA, eB;
                eA[0] = __expf(preA[jj].x); eA[1] = __expf(preA[jj].y);
                eA[2] = __expf(preA[jj].z); eA[3] = __expf(preA[jj].w);
                eB[0] = __expf(preB[jj].x); eB[1] = __expf(preB[jj].y);
                eB[2] = __expf(preB[jj].z); eB[3] = __expf(preB[jj].w);
                *(float4v*)&ebA[(jj * 64 + lane) * 4] = eA;
                *(float4v*)&ebB[(jj * 64 + lane) * 4] = eB;
            }
        } else {
            const float4* gA = (const float4*)(yp + (size_t)(tbA + STL) * K32);
            const float4* gB = (const float4*)(yp + (size_t)(tbB + STL) * K32);
#pragma unroll
            for (int jj = 0; jj < 4; ++jj) {
                const float4 pA = gA[jj * 64 + lane];
                const float4 pB = gB[jj * 64 + lane];
                float4v eA, eB;
                eA[0] = __expf(pA.x); eA[1] = __expf(pA.y);
                eA[2] = __expf(pA.z); eA[3] = __expf(pA.w);
                eB[0] = __expf(pB.x); eB[1] = __expf(pB.y);
                eB[2] = __expf(pB.z); eB[3] = __expf(pB.w);
                *(float4v*)&ebA[(jj * 64 + lane) * 4] = eA;
                *(float4v*)&ebB[(jj * 64 + lane) * 4] = eB;
            }
        }

        const unsigned bA = (unsigned)(mbA >> (st * 32));
        const unsigned bB = (unsigned)(mbB >> (st * 32));
        if (bA == 0xFFFFFFFFu && bB == 0xFFFFFFFFu) {
            // branch-free fast path: 8 independent MFMAs per step-pair
            for (int g = 0; g < 4; ++g) {
                const int i0 = g * 8;
                stepone(ebA, BA0, BA1, i0 + 0, false); stepone(ebB, BB0, BB1, i0 + 0, false);
                stepone(ebA, BA0, BA1, i0 + 1, false); stepone(ebB, BB0, BB1, i0 + 1, false);
                stepone(ebA, BA0, BA1, i0 + 2, false); stepone(ebB, BB0, BB1, i0 + 2, false);
                stepone(ebA, BA0, BA1, i0 + 3, false); stepone(ebB, BB0, BB1, i0 + 3, false);
                stepone(ebA, BA0, BA1, i0 + 4, false); stepone(ebB, BB0, BB1, i0 + 4, false);
                stepone(ebA, BA0, BA1, i0 + 5, false); stepone(ebB, BB0, BB1, i0 + 5, false);
                stepone(ebA, BA0, BA1, i0 + 6, false); stepone(ebB, BB0, BB1, i0 + 6, false);
                stepone(ebA, BA0, BA1, i0 + 7, true);  stepone(ebB, BB0, BB1, i0 + 7, true);
            }
        } else if (bA == 0xFFFFFFFEu && bB == 0xFFFFFFFFu) {
            // wave-0 stage-0 common case: chunk A skips step 0
            for (int g = 0; g < 4; ++g) {
                const int i0 = g * 8;
                if (g != 0) stepone(ebA, BA0, BA1, i0 + 0, false);
                stepone(ebB, BB0, BB1, i0 + 0, false);
                stepone(ebA, BA0, BA1, i0 + 1, false); stepone(ebB, BB0, BB1, i0 + 1, false);
                stepone(ebA, BA0, BA1, i0 + 2, false); stepone(ebB, BB0, BB1, i0 + 2, false);
                stepone(ebA, BA0, BA1, i0 + 3, false); stepone(ebB, BB0, BB1, i0 + 3, false);
                stepone(ebA, BA0, BA1, i0 + 4, false); stepone(ebB, BB0, BB1, i0 + 4, false);
                stepone(ebA, BA0, BA1, i0 + 5, false); stepone(ebB, BB0, BB1, i0 + 5, false);
                stepone(ebA, BA0, BA1, i0 + 6, false); stepone(ebB, BB0, BB1, i0 + 6, false);
                stepone(ebA, BA0, BA1, i0 + 7, true);  stepone(ebB, BB0, BB1, i0 + 7, true);
            }
        } else {
            for (int i = 0; i < STL; ++i) {
                const bool ren = (i & 7) == 7;
                if ((bA >> i) & 1u) stepone(ebA, BA0, BA1, i, ren);
                if ((bB >> i) & 1u) stepone(ebB, BB0, BB1, i, ren);
            }
        }
    }

    // ---- two sequential transposes in the dead staging LDS ----
    {
        unsigned* scr = (unsigned*)ebA + 1024;    // 640-dword scratch, stride 20
        unsigned* md  = (unsigned*)ebA;           // M^T A -> [0..511], B -> [512..1023]

        // chunk A
        *(uint2*)&scr[n * 20 + q * 2]            = make_uint2(BA0.u[0], BA0.u[1]);
        *(uint2*)&scr[n * 20 + 8 + q * 2]        = make_uint2(BA0.u[2], BA0.u[3]);
        *(uint2*)&scr[(16 + n) * 20 + q * 2]     = make_uint2(BA1.u[0], BA1.u[1]);
        *(uint2*)&scr[(16 + n) * 20 + 8 + q * 2] = make_uint2(BA1.u[2], BA1.u[3]);
        const unsigned short* NcA = (const unsigned short*)scr;
        unsigned rA[8];
#pragma unroll
        for (int ii = 0; ii < 8; ++ii) {
            const int idx = ii * 64 + lane;
            const int k = idx >> 4, d = idx & 15;
            rA[ii] = (unsigned)NcA[(2 * d) * 40 + k] |
                     ((unsigned)NcA[(2 * d + 1) * 40 + k] << 16);
        }
#pragma unroll
        for (int ii = 0; ii < 8; ++ii) md[ii * 64 + lane] = rA[ii];

        // chunk B (scratch reuse after A's reads complete — program order)
        *(uint2*)&scr[n * 20 + q * 2]            = make_uint2(BB0.u[0], BB0.u[1]);
        *(uint2*)&scr[n * 20 + 8 + q * 2]        = make_uint2(BB0.u[2], BB0.u[3]);
        *(uint2*)&scr[(16 + n) * 20 + q * 2]     = make_uint2(BB1.u[0], BB1.u[1]);
        *(uint2*)&scr[(16 + n) * 20 + 8 + q * 2] = make_uint2(BB1.u[2], BB1.u[3]);
        const unsigned short* NcB = (const unsigned short*)scr;
        unsigned rB[8];
#pragma unroll
        for (int ii = 0; ii < 8; ++ii) {
            const int idx = ii * 64 + lane;
            const int k = idx >> 4, d = idx & 15;
            rB[ii] = (unsigned)NcB[(2 * d) * 40 + k] |
                     ((unsigned)NcB[(2 * d + 1) * 40 + k] << 16);
        }
#pragma unroll
        for (int ii = 0; ii < 8; ++ii) md[512 + ii * 64 + lane] = rB[ii];
    }
    if (lane == 0) {
        sAux[wv]     = (float)eSum * 0.693147180559945f + (float)applied * 3.46573590f;
        sAux[4 + wv] = sc;
    }

    __syncthreads();

    // ---------------- combine (wave 0 only): 8 serial matvecs + logsumexp ----------------
    if (wv == 0) {
        const int h = lane >> 5;
        const int j = lane & 31;

        auto mt = [&](int cc) -> const unsigned* {
            return (const unsigned*)&expAll[cc >> 1][0] + ((cc & 1) << 9);
        };

        // rolling 1-chunk register prefetch of M^T row j halves
        uint4 cA = *(const uint4*)&mt(0)[j * 16 + 8 * h];
        uint4 cB = *(const uint4*)&mt(0)[j * 16 + 8 * h + 4];

        const float a0 = yp[j];                // mirrored in both halves
        const float m0 = __shfl(a0, 0, 64);
        float p = __expf(a0 - m0);             // p[j], mirrored
        float S = m0;

        float scs = 0.0f;
#pragma unroll
        for (int w = 0; w < 4; ++w) { S += sAux[w]; scs += sAux[4 + w]; }

        const int cb = h << 4;                 // column base for this half
#pragma unroll
        for (int cc = 0; cc < NCH; ++cc) {
            uint4 nA = {0, 0, 0, 0}, nB = {0, 0, 0, 0};
            if (cc + 1 < NCH) {
                nA = *(const uint4*)&mt(cc + 1)[j * 16 + 8 * h];
                nB = *(const uint4*)&mt(cc + 1)[j * 16 + 8 * h + 4];
            }
            const float cn = __shfl(p, 0, 64); // old p[0] (deferred renorm)
            const unsigned u0 = cA.x, u1 = cA.y, u2 = cA.z, u3 = cA.w;
            const unsigned u4 = cB.x, u5 = cB.y, u6 = cB.z, u7 = cB.w;
            float acc = 0.0f;
            acc = fmaf(__shfl(p, cb +  0, 64), bf2f_lo(u0), acc);
            acc = fmaf(__shfl(p, cb +  1, 64), bf2f_hi(u0), acc);
            acc = fmaf(__shfl(p, cb +  2, 64), bf2f_lo(u1), acc);
            acc = fmaf(__shfl(p, cb +  3, 64), bf2f_hi(u1), acc);
            acc = fmaf(__shfl(p, cb +  4, 64), bf2f_lo(u2), acc);
            acc = fmaf(__shfl(p, cb +  5, 64), bf2f_hi(u2), acc);
            acc = fmaf(__shfl(p, cb +  6, 64), bf2f_lo(u3), acc);
            acc = fmaf(__shfl(p, cb +  7, 64), bf2f_hi(u3), acc);
            acc = fmaf(__shfl(p, cb +  8, 64), bf2f_lo(u4), acc);
            acc = fmaf(__shfl(p, cb +  9, 64), bf2f_hi(u4), acc);
            acc = fmaf(__shfl(p, cb + 10, 64), bf2f_lo(u5), acc);
            acc = fmaf(__shfl(p, cb + 11, 64), bf2f_hi(u5), acc);
            acc = fmaf(__shfl(p, cb + 12, 64), bf2f_lo(u6), acc);
            acc = fmaf(__shfl(p, cb + 13, 64), bf2f_hi(u6), acc);
            acc = fmaf(__shfl(p, cb + 14, 64), bf2f_lo(u7), acc);
            acc = fmaf(__shfl(p, cb + 15, 64), bf2f_hi(u7), acc);
            acc += __shfl_xor(acc, 32, 64);    // combine halves -> full dot, mirrored
            p = acc * (1.0f / cn);
            S += __logf(cn);
            cA = nA; cB = nB;
        }

        float sp = p;
        sp += __shfl_xor(sp,  1, 64);
        sp += __shfl_xor(sp,  2, 64);
        sp += __shfl_xor(sp,  4, 64);
        sp += __shfl_xor(sp,  8, 64);
        sp += __shfl_xor(sp, 16, 64);

        if (lane == 0) {
            out[seq] = S + __logf(sp) - scs;
        }
    }
}

extern "C" void kernel_launch(void* const* d_in, const int* in_sizes, int n_in,
                              void* d_out, int out_size, void* d_ws, size_t ws_size,
                              hipStream_t stream) {
    const int*   labels = (const int*)  d_in[0];
    const float* y_pred = (const float*)d_in[1];
    const float* trans  = (const float*)d_in[2];
    const float* mask   = (const float*)d_in[3];
    float* out = (float*)d_out;

    crf_fused<<<1024, 256, 0, stream>>>(labels, y_pred, trans, mask, out);
}